// Round 1
// baseline (626.437 us; speedup 1.0000x reference)
//
#include <hip/hip_runtime.h>
#include <math.h>

// Problem constants (from reference)
#define NDIM 64
#define NK   128
#define ALPHA_DP 1.0
#define TAU0 0.0
#define C0v  1.0
#define N0v  ((double)(NDIM + 2))
#define B0v  1.0

// ---------------- device math helpers (double) ----------------
__device__ double digamma_d(double x) {
    double r = 0.0;
    while (x < 6.0) { r -= 1.0 / x; x += 1.0; }
    double inv = 1.0 / x, inv2 = inv * inv;
    double s = log(x) - 0.5 * inv
        - inv2 * (1.0/12.0 - inv2 * (1.0/120.0 - inv2 * (1.0/252.0
            - inv2 * (1.0/240.0 - inv2 * (1.0/132.0)))));
    return s + r;
}

// ---------------- kernel 1: cluster prep (1 block, K threads) ----------------
// ws layout: [0]=ll accumulator (double), [1]=kl total (double),
//            then const_k (K floats), nbT (D*K floats, d-major), w2T (D*K floats)
__global__ void prep_kernel(const float* __restrict__ nat_u,
                            const float* __restrict__ nat_v,
                            const float* __restrict__ nat_tau,
                            const float* __restrict__ nat_c,
                            const float* __restrict__ nat_n,
                            const float* __restrict__ nat_B,
                            double* __restrict__ scal,
                            float* __restrict__ constk,
                            float* __restrict__ nbT,
                            float* __restrict__ w2T) {
    const int k = threadIdx.x;          // 0..K-1
    const int D = NDIM, K = NK;

    double u = (double)nat_u[k] + 1.0;
    double v = (double)nat_v[k] + 1.0;
    double c = (double)nat_c[k];
    double n = (double)nat_n[k] - (double)D - 2.0;

    double dg_u  = digamma_d(u);
    double dg_v  = digamma_d(v);
    double dg_uv = digamma_d(u + v);

    const double a0g = 0.5 * N0v;       // prior Gamma shape
    const double b0g = 0.5 * B0v;       // prior Gamma rate-ish scale
    double sum_log_halfB = 0.0, sum_t2nb = 0.0, sum_nb = 0.0;
    double kl_g_d = 0.0, kl_n_d = 0.0;

    for (int d = 0; d < D; ++d) {
        double tau = (double)nat_tau[k * D + d] / c;
        double B   = (double)nat_B[k * D + d] - c * tau * tau;
        double nb  = n / B;
        nbT[d * K + k] = (float)nb;
        w2T[d * K + k] = (float)(-2.0 * tau * nb);
        sum_log_halfB += log(0.5 * B);
        sum_t2nb += tau * tau * nb;
        sum_nb   += nb;
        double b1 = 0.5 * B;
        kl_g_d += a0g * (log(b1) - log(b0g)) + (0.5 * n) * (b0g - b1) / b1;
        kl_n_d += C0v * nb * (tau - TAU0) * (tau - TAU0);
    }

    double a1 = 0.5 * n;
    double e_log_det = (double)D * digamma_d(a1) - sum_log_halfB;

    // stick-breaking exclusive prefix of E[log(1-s)]
    __shared__ double sh[NK];
    sh[k] = dg_v - dg_uv;
    __syncthreads();
    double pre = 0.0;
    for (int j = 0; j < k; ++j) pre += sh[j];
    double e_log_pi = dg_u - dg_uv + pre;

    // const_k folds: e_log_pi + 0.5*(e_log_det - D log 2pi - sum tau^2 nb - D/c - sum_nb)
    // (sum_nb folded because main kernel accumulates nb*(x^2-1) for fp32 accuracy)
    const double LOG2PI = 1.8378770664093454836;
    double ck = e_log_pi + 0.5 * (e_log_det - (double)D * LOG2PI
                                  - sum_t2nb - (double)D / c - sum_nb);
    constk[k] = (float)ck;

    // KL terms
    const double a0 = 1.0, b0 = ALPHA_DP;
    double kl_beta = lgamma(u + v) - lgamma(u) - lgamma(v)
        - (lgamma(a0 + b0) - lgamma(a0) - lgamma(b0))
        + (u - a0) * dg_u + (v - b0) * dg_v + (a0 + b0 - u - v) * dg_uv;

    double dga1 = digamma_d(a1);
    double kl_gamma = (double)D * ((a1 - a0g) * dga1 - lgamma(a1) + lgamma(a0g)) + kl_g_d;

    double kl_norm = 0.5 * ((double)D * (log(c / C0v) + C0v / c - 1.0) + kl_n_d);

    __syncthreads();
    sh[k] = kl_beta + kl_gamma + kl_norm;
    __syncthreads();
    if (k == 0) {
        double t = 0.0;
        for (int j = 0; j < K; ++j) t += sh[j];
        scal[1] = t;     // kl total
        scal[0] = 0.0;   // ll accumulator (zero every call; ws is poisoned)
    }
}

// ---------------- kernel 2: maha GEMM + fused softmax ----------------
// Block: 256 threads; tile = 64 points x 128 clusters; thread tile 8p x 4k.
#define MP 64
#define BD 32
__global__ __launch_bounds__(256) void maha_kernel(
    const float* __restrict__ x,
    const float* __restrict__ constk,
    const float* __restrict__ nbT,
    const float* __restrict__ w2T,
    float* __restrict__ r,
    double* __restrict__ scal) {
    const int K = NK, D = NDIM;
    const int tid = threadIdx.x;
    const int tx = tid & 31;      // cluster group: covers k = tx*4 .. tx*4+3
    const int ty = tid >> 5;      // point group:  covers p = ty*8 .. ty*8+7
    const long n0 = (long)blockIdx.x * MP;

    __shared__ __align__(16) float xs[BD][68];   // [d][point], padded
    __shared__ __align__(16) float snb[BD][NK];  // [d][k]
    __shared__ __align__(16) float sw2[BD][NK];
    __shared__ float sck[NK];

    float acc[8][4];
#pragma unroll
    for (int p = 0; p < 8; ++p)
#pragma unroll
        for (int j = 0; j < 4; ++j) acc[p][j] = 0.f;

    if (tid < K) sck[tid] = constk[tid];

    for (int ch = 0; ch < D / BD; ++ch) {
        const int d0 = ch * BD;
        // stage x tile (transpose to [d][p]); 512 float4 over 256 threads
#pragma unroll
        for (int it = 0; it < 2; ++it) {
            int f4i = it * 256 + tid;
            int p = f4i >> 3, dq = f4i & 7;
            float4 xv = *(const float4*)(x + (n0 + p) * D + d0 + dq * 4);
            xs[dq * 4 + 0][p] = xv.x;
            xs[dq * 4 + 1][p] = xv.y;
            xs[dq * 4 + 2][p] = xv.z;
            xs[dq * 4 + 3][p] = xv.w;
        }
        // stage nb / w2 tiles (already d-major in ws; straight copy)
#pragma unroll
        for (int it = 0; it < 4; ++it) {
            int fi = (it * 256 + tid) * 4;
            *(float4*)((float*)snb + fi) = *(const float4*)(nbT + d0 * K + fi);
            *(float4*)((float*)sw2 + fi) = *(const float4*)(w2T + d0 * K + fi);
        }
        __syncthreads();

#pragma unroll 8
        for (int d = 0; d < BD; ++d) {
            float4 xa = *(float4*)&xs[d][ty * 8];
            float4 xb = *(float4*)&xs[d][ty * 8 + 4];
            float4 nv = *(float4*)&snb[d][tx * 4];
            float4 wv = *(float4*)&sw2[d][tx * 4];
            float xp[8] = {xa.x, xa.y, xa.z, xa.w, xb.x, xb.y, xb.z, xb.w};
            float nb4[4] = {nv.x, nv.y, nv.z, nv.w};
            float w4[4]  = {wv.x, wv.y, wv.z, wv.w};
            float yp[8];
#pragma unroll
            for (int p = 0; p < 8; ++p) yp[p] = fmaf(xp[p], xp[p], -1.0f); // x^2-1 (centered)
#pragma unroll
            for (int p = 0; p < 8; ++p)
#pragma unroll
                for (int j = 0; j < 4; ++j) {
                    float t = fmaf(nb4[j], yp[p], acc[p][j]);
                    acc[p][j] = fmaf(w4[j], xp[p], t);
                }
        }
        __syncthreads();
    }

    // fused epilogue: per-point logsumexp across the 32 tx-threads (masks<32 stay in-half)
    double lsum = 0.0;
#pragma unroll
    for (int p = 0; p < 8; ++p) {
        float lr[4];
        float m = -3.4e38f;
#pragma unroll
        for (int j = 0; j < 4; ++j) {
            lr[j] = sck[tx * 4 + j] - 0.5f * acc[p][j];
            m = fmaxf(m, lr[j]);
        }
#pragma unroll
        for (int msk = 16; msk >= 1; msk >>= 1) m = fmaxf(m, __shfl_xor(m, msk, 64));
        float s = 0.f;
#pragma unroll
        for (int j = 0; j < 4; ++j) { lr[j] = __expf(lr[j] - m); s += lr[j]; }
#pragma unroll
        for (int msk = 16; msk >= 1; msk >>= 1) s += __shfl_xor(s, msk, 64);
        float inv = 1.0f / s;
        float4 rv = make_float4(lr[0] * inv, lr[1] * inv, lr[2] * inv, lr[3] * inv);
        *(float4*)(r + (n0 + ty * 8 + p) * (long)K + tx * 4) = rv;
        if (tx == 0) lsum += (double)m + (double)logf(s);
    }
    if (tx == 0) atomicAdd(scal, lsum);   // device-scope f64 atomic
}

// ---------------- kernel 3: finalize scalar ----------------
__global__ void finalize_kernel(const double* __restrict__ scal, float* __restrict__ out) {
    // -elbo = kl_total - ll
    out[0] = (float)(scal[1] - scal[0]);
}

extern "C" void kernel_launch(void* const* d_in, const int* in_sizes, int n_in,
                              void* d_out, int out_size, void* d_ws, size_t ws_size,
                              hipStream_t stream) {
    const float* x       = (const float*)d_in[0];
    const float* nat_u   = (const float*)d_in[1];
    const float* nat_v   = (const float*)d_in[2];
    const float* nat_tau = (const float*)d_in[3];
    const float* nat_c   = (const float*)d_in[4];
    const float* nat_n   = (const float*)d_in[5];
    const float* nat_B   = (const float*)d_in[6];

    const int D = NDIM, K = NK;
    const int N = in_sizes[0] / D;

    float* out = (float*)d_out;

    // ws layout (66,064 bytes used)
    double* scal  = (double*)d_ws;
    float* constk = (float*)((char*)d_ws + 16);
    float* nbT    = constk + K;        // offset 528 B, 16B aligned
    float* w2T    = nbT + (size_t)K * D;

    prep_kernel<<<1, K, 0, stream>>>(nat_u, nat_v, nat_tau, nat_c, nat_n, nat_B,
                                     scal, constk, nbT, w2T);
    maha_kernel<<<N / MP, 256, 0, stream>>>(x, constk, nbT, w2T, out, scal);
    finalize_kernel<<<1, 1, 0, stream>>>(scal, out + (size_t)N * K);
}

// Round 2
// 412.079 us; speedup vs baseline: 1.5202x; 1.5202x over previous
//
#include <hip/hip_runtime.h>
#include <math.h>

// Problem constants (from reference)
#define NDIM 64
#define NK   128
#define ALPHA_DP 1.0
#define TAU0 0.0
#define C0v  1.0
#define N0v  ((double)(NDIM + 2))
#define B0v  1.0

// ---------------- device math helpers (double) ----------------
__device__ double digamma_d(double x) {
    double r = 0.0;
    while (x < 6.0) { r -= 1.0 / x; x += 1.0; }
    double inv = 1.0 / x, inv2 = inv * inv;
    double s = log(x) - 0.5 * inv
        - inv2 * (1.0/12.0 - inv2 * (1.0/120.0 - inv2 * (1.0/252.0
            - inv2 * (1.0/240.0 - inv2 * (1.0/132.0)))));
    return s + r;
}

// ---------------- kernel 1: cluster prep (1 block, K threads) ----------------
// ws layout: [0]=ll accumulator (double), [1]=kl total (double),
//            constk (K floats), nbD (D*K floats, d-major), w2D (D*K floats, d-major)
__global__ void prep_kernel(const float* __restrict__ nat_u,
                            const float* __restrict__ nat_v,
                            const float* __restrict__ nat_tau,
                            const float* __restrict__ nat_c,
                            const float* __restrict__ nat_n,
                            const float* __restrict__ nat_B,
                            double* __restrict__ scal,
                            float* __restrict__ constk,
                            float* __restrict__ nbD,
                            float* __restrict__ w2D) {
    const int k = threadIdx.x;          // 0..K-1
    const int D = NDIM, K = NK;

    double u = (double)nat_u[k] + 1.0;
    double v = (double)nat_v[k] + 1.0;
    double c = (double)nat_c[k];
    double n = (double)nat_n[k] - (double)D - 2.0;

    double dg_u  = digamma_d(u);
    double dg_v  = digamma_d(v);
    double dg_uv = digamma_d(u + v);

    const double a0g = 0.5 * N0v;
    const double b0g = 0.5 * B0v;
    double sum_log_halfB = 0.0, sum_t2nb = 0.0, sum_nb = 0.0;
    double kl_g_d = 0.0, kl_n_d = 0.0;

    for (int d = 0; d < D; ++d) {
        double tau = (double)nat_tau[k * D + d] / c;
        double B   = (double)nat_B[k * D + d] - c * tau * tau;
        double nb  = n / B;
        nbD[d * K + k] = (float)nb;                 // d-major for the maha kernel
        w2D[d * K + k] = (float)(-2.0 * tau * nb);
        sum_log_halfB += log(0.5 * B);
        sum_t2nb += tau * tau * nb;
        sum_nb   += nb;
        double b1 = 0.5 * B;
        kl_g_d += a0g * (log(b1) - log(b0g)) + (0.5 * n) * (b0g - b1) / b1;
        kl_n_d += C0v * nb * (tau - TAU0) * (tau - TAU0);
    }

    double a1 = 0.5 * n;
    double e_log_det = (double)D * digamma_d(a1) - sum_log_halfB;

    // stick-breaking exclusive prefix of E[log(1-s)]
    __shared__ double sh[NK];
    sh[k] = dg_v - dg_uv;
    __syncthreads();
    double pre = 0.0;
    for (int j = 0; j < k; ++j) pre += sh[j];
    double e_log_pi = dg_u - dg_uv + pre;

    // const_k folds e_log_pi + 0.5*(e_log_det - D log 2pi - sum tau^2 nb - D/c - sum_nb)
    // (sum_nb folded because main kernel accumulates nb*(x^2-1) for fp32 accuracy)
    const double LOG2PI = 1.8378770664093454836;
    double ck = e_log_pi + 0.5 * (e_log_det - (double)D * LOG2PI
                                  - sum_t2nb - (double)D / c - sum_nb);
    constk[k] = (float)ck;

    // KL terms
    const double a0 = 1.0, b0 = ALPHA_DP;
    double kl_beta = lgamma(u + v) - lgamma(u) - lgamma(v)
        - (lgamma(a0 + b0) - lgamma(a0) - lgamma(b0))
        + (u - a0) * dg_u + (v - b0) * dg_v + (a0 + b0 - u - v) * dg_uv;

    double dga1 = digamma_d(a1);
    double kl_gamma = (double)D * ((a1 - a0g) * dga1 - lgamma(a1) + lgamma(a0g)) + kl_g_d;

    double kl_norm = 0.5 * ((double)D * (log(c / C0v) + C0v / c - 1.0) + kl_n_d);

    __syncthreads();
    sh[k] = kl_beta + kl_gamma + kl_norm;
    __syncthreads();
    if (k == 0) {
        double t = 0.0;
        for (int j = 0; j < K; ++j) t += sh[j];
        scal[1] = t;     // kl total
        scal[0] = 0.0;   // ll accumulator (ws is poisoned every call)
    }
}

// ---------------- kernel 2: per-point broadcast-FMA + fused softmax ----------------
// One point per lane. Coefficients are wave-uniform -> s_load (SGPR) stream; the
// inner loop is pure v_fmac v_acc, s_coef, v_x. No LDS, no barriers.
__global__ __launch_bounds__(256) void maha_kernel(
    const float* __restrict__ x,
    const float* __restrict__ constk,
    const float* __restrict__ nbD,     // [d][k]
    const float* __restrict__ w2D,     // [d][k]
    float* __restrict__ r,
    double* __restrict__ scal) {
    const int K = NK, D = NDIM;
    const int tid = threadIdx.x;
    const long n = (long)blockIdx.x * 256 + tid;
    const float* __restrict__ xp = x + n * D;

    float acc[NK];
#pragma unroll
    for (int k = 0; k < NK; ++k) acc[k] = 0.f;

    float xd = xp[0];                   // prefetched current-x
    for (int d = 0; d < D; ++d) {
        float xn = (d < D - 1) ? xp[d + 1] : 0.f;   // prefetch next (hidden under body)
        float yd = fmaf(xd, xd, -1.0f);             // centered x^2 (accuracy)
        const float* __restrict__ cw = w2D + (d << 7);  // wave-uniform address
        const float* __restrict__ cn = nbD + (d << 7);
#pragma unroll
        for (int k = 0; k < NK; ++k) {
            float t = fmaf(cw[k], xd, acc[k]);      // v_fmac vacc, s_w2, v_x
            acc[k] = fmaf(cn[k], yd, t);            // v_fmac vacc, s_nb, v_y
        }
        xd = xn;
    }

    // logits: lr[k] = constk[k] - 0.5*acc[k]; softmax over k within this thread
    float m = -3.4e38f;
#pragma unroll
    for (int k = 0; k < NK; ++k) {
        acc[k] = fmaf(acc[k], -0.5f, constk[k]);    // constk wave-uniform -> SGPR
        m = fmaxf(m, acc[k]);
    }
    float s = 0.f;
#pragma unroll
    for (int k = 0; k < NK; ++k) {
        acc[k] = __expf(acc[k] - m);
        s += acc[k];
    }
    float inv = 1.0f / s;
    float* __restrict__ rp = r + n * K;
#pragma unroll
    for (int q = 0; q < NK / 4; ++q) {
        float4 v = make_float4(acc[4 * q] * inv, acc[4 * q + 1] * inv,
                               acc[4 * q + 2] * inv, acc[4 * q + 3] * inv);
        *(float4*)(rp + 4 * q) = v;
    }

    // ll contribution: log_norm = m + log(s); reduce across the wave, one atomic/wave
    double ln = (double)m + log((double)s);
#pragma unroll
    for (int off = 32; off >= 1; off >>= 1) ln += __shfl_xor(ln, off, 64);
    if ((tid & 63) == 0) atomicAdd(scal, ln);
}

// ---------------- kernel 3: finalize scalar ----------------
__global__ void finalize_kernel(const double* __restrict__ scal, float* __restrict__ out) {
    out[0] = (float)(scal[1] - scal[0]);   // -elbo = kl_total - ll
}

extern "C" void kernel_launch(void* const* d_in, const int* in_sizes, int n_in,
                              void* d_out, int out_size, void* d_ws, size_t ws_size,
                              hipStream_t stream) {
    const float* x       = (const float*)d_in[0];
    const float* nat_u   = (const float*)d_in[1];
    const float* nat_v   = (const float*)d_in[2];
    const float* nat_tau = (const float*)d_in[3];
    const float* nat_c   = (const float*)d_in[4];
    const float* nat_n   = (const float*)d_in[5];
    const float* nat_B   = (const float*)d_in[6];

    const int D = NDIM, K = NK;
    const int N = in_sizes[0] / D;

    float* out = (float*)d_out;

    // ws layout (~66 KB used)
    double* scal  = (double*)d_ws;
    float* constk = (float*)((char*)d_ws + 16);
    float* nbD    = constk + K;               // 528 B offset, 16B-aligned
    float* w2D    = nbD + (size_t)K * D;

    prep_kernel<<<1, K, 0, stream>>>(nat_u, nat_v, nat_tau, nat_c, nat_n, nat_B,
                                     scal, constk, nbD, w2D);
    maha_kernel<<<N / 256, 256, 0, stream>>>(x, constk, nbD, w2D, out, scal);
    finalize_kernel<<<1, 1, 0, stream>>>(scal, out + (size_t)N * K);
}